// Round 3
// baseline (4265.562 us; speedup 1.0000x reference)
//
#include <hip/hip_runtime.h>
#include <hip/hip_bf16.h>

#define BATCH 64
#define SEQ 2048
#define IN_DIM 256
#define UNITS 256

typedef _Float16 half2_t __attribute__((ext_vector_type(2)));

__device__ __forceinline__ float fdot2(half2_t a, half2_t b, float c) {
#if __has_builtin(__builtin_amdgcn_fdot2)
    return __builtin_amdgcn_fdot2(a, b, c, false);
#else
    return c + (float)a[0] * (float)b[0] + (float)a[1] * (float)b[1];
#endif
}

// DPP butterfly add; after the 3 steps all 8 lanes of a consecutive 8-lane
// group hold the group sum.
template <int CTRL>
__device__ __forceinline__ float dpp_xor_add(float v) {
    int s = __builtin_amdgcn_update_dpp(0, __float_as_int(v), CTRL, 0xF, 0xF, true);
    return v + __int_as_float(s);
}
__device__ __forceinline__ float row8_sum(float v) {
    v = dpp_xor_add<0xB1>(v);    // quad_perm {1,0,3,2} : xor 1
    v = dpp_xor_add<0x4E>(v);    // quad_perm {2,3,0,1} : xor 2
    v = dpp_xor_add<0x141>(v);   // row_half_mirror     : pairs the two quads
    return v;
}

// CK-style barrier: drains LDS ops only; global loads stay IN FLIGHT across
// the barrier (no vmcnt(0) drain like __syncthreads emits).
#define BAR() asm volatile("s_waitcnt lgkmcnt(0)\n\ts_barrier" ::: "memory")

// ---------------------------------------------------------------------------
// Prep: transpose U_f, U_s (K x U, fp32) -> Ut (U x K, f16).
// ---------------------------------------------------------------------------
__global__ void prep_u(const float* __restrict__ Uf, const float* __restrict__ Us,
                       _Float16* __restrict__ Utf, _Float16* __restrict__ Uts) {
    int idx = blockIdx.x * 256 + threadIdx.x;   // 65536 total
    int k = idx >> 8;
    int u = idx & 255;
    Utf[u * 256 + k] = (_Float16)Uf[idx];
    Uts[u * 256 + k] = (_Float16)Us[idx];
}

// ---------------------------------------------------------------------------
// Projection GEMM (unchanged): 64x64 tile, fp32.
// ---------------------------------------------------------------------------
__global__ __launch_bounds__(256) void proj_kernel(
    const float* __restrict__ X,
    const float* __restrict__ Wf, const float* __restrict__ bf,
    const float* __restrict__ Wsm, const float* __restrict__ bs,
    float* __restrict__ xf_out, _Float16* __restrict__ xs_out)
{
    __shared__ float Xs[64][65];
    __shared__ float Wsh[64][68];

    const int tid = threadIdx.x;
    const int rt = blockIdx.x;
    const int ct = blockIdx.y;
    const int r0 = rt * 64;
    const bool is_f = ct < 4;
    const int c0 = (ct & 3) * 64;
    const float* W = is_f ? Wf : Wsm;
    const float* bias = is_f ? bf : bs;
    const int tx = tid & 15;
    const int ty = tid >> 4;

    float acc[4][4];
#pragma unroll
    for (int i = 0; i < 4; ++i)
#pragma unroll
        for (int j = 0; j < 4; ++j) acc[i][j] = 0.f;

    for (int kc = 0; kc < IN_DIM; kc += 64) {
        __syncthreads();
#pragma unroll
        for (int i = 0; i < 4; ++i) {
            int f = tid + i * 256;
            int row = f >> 4;
            int kq = f & 15;
            float4 v = *(const float4*)(X + (size_t)(r0 + row) * IN_DIM + kc + kq * 4);
            Xs[row][kq * 4 + 0] = v.x;
            Xs[row][kq * 4 + 1] = v.y;
            Xs[row][kq * 4 + 2] = v.z;
            Xs[row][kq * 4 + 3] = v.w;
        }
#pragma unroll
        for (int i = 0; i < 4; ++i) {
            int f = tid + i * 256;
            int kk = f >> 4;
            int n4 = f & 15;
            float4 v = *(const float4*)(W + (size_t)(kc + kk) * UNITS + c0 + n4 * 4);
            *(float4*)&Wsh[kk][n4 * 4] = v;
        }
        __syncthreads();
#pragma unroll 8
        for (int kk = 0; kk < 64; ++kk) {
            float a0 = Xs[tx * 4 + 0][kk];
            float a1 = Xs[tx * 4 + 1][kk];
            float a2 = Xs[tx * 4 + 2][kk];
            float a3 = Xs[tx * 4 + 3][kk];
            float4 bv = *(const float4*)&Wsh[kk][ty * 4];
            acc[0][0] += a0 * bv.x; acc[0][1] += a0 * bv.y; acc[0][2] += a0 * bv.z; acc[0][3] += a0 * bv.w;
            acc[1][0] += a1 * bv.x; acc[1][1] += a1 * bv.y; acc[1][2] += a1 * bv.z; acc[1][3] += a1 * bv.w;
            acc[2][0] += a2 * bv.x; acc[2][1] += a2 * bv.y; acc[2][2] += a2 * bv.z; acc[2][3] += a2 * bv.w;
            acc[3][0] += a3 * bv.x; acc[3][1] += a3 * bv.y; acc[3][2] += a3 * bv.z; acc[3][3] += a3 * bv.w;
        }
    }

#pragma unroll
    for (int i = 0; i < 4; ++i) {
        int r = r0 + tx * 4 + i;
        int n0 = c0 + ty * 4;
        if (is_f) {
            float4 v;
            v.x = acc[i][0] + bias[n0 + 0];
            v.y = acc[i][1] + bias[n0 + 1];
            v.z = acc[i][2] + bias[n0 + 2];
            v.w = acc[i][3] + bias[n0 + 3];
            *(float4*)(xf_out + (size_t)r * UNITS + n0) = v;
        } else {
#pragma unroll
            for (int j = 0; j < 4; ++j)
                xs_out[(size_t)r * UNITS + n0 + j] = (_Float16)(acc[i][j] + bias[n0 + j]);
        }
    }
}

// ---------------------------------------------------------------------------
// Recurrence v3: one block (1024 thr) per batch, 2 barriers/step.
// Thread (wave w, r=lane>>3, g=lane&7) covers u = 16w+2r+{0,1} over
// k-slice [32g, 32g+32).
//   - h/g read from LDS: 4 x ds_read_b128 per lane per phase, stride-40-f16
//     groups -> conflict-free.
//   - k-partials reduced over the 8 g-lanes via DPP (3 steps).
//   - gates applied IN-WAVE by the g==0 lanes (no sum round-trip, no extra
//     barrier); h_old / f persist in those lanes' registers.
//   - raw s_barrier (lgkmcnt-only drain) so the 1-step-ahead xf/xs register
//     prefetch stays in flight across barriers.
// ---------------------------------------------------------------------------
__global__ __launch_bounds__(1024) void recur_kernel(
    float* xf_out,                       // aliases d_out: xf in, h out (no restrict!)
    const _Float16* __restrict__ xs16,   // [B][T][U]
    const _Float16* __restrict__ Utf,    // [U][K] f16
    const _Float16* __restrict__ Uts)    // [U][K] f16
{
    __shared__ __align__(16) _Float16 h2p[8 * 40];   // 8 k-groups x 32 f16 (+8 pad)
    __shared__ __align__(16) _Float16 g2p[8 * 40];

    const int tid = threadIdx.x;
    const int w = tid >> 6;
    const int lane = tid & 63;
    const int g = lane & 7;         // k-group: k in [32g, 32g+32)
    const int r = lane >> 3;        // 0..7
    const int u0 = 16 * w + 2 * r;  // two outputs: u0, u0+1
    const int b = blockIdx.x;

    union F4H { float4 f4; half2_t h[4]; };
    union U2H { unsigned u; half2_t h; };

    // Register-resident weight slices: 16 half2 per u per matrix.
    half2_t uf[2][16], us[2][16];
#pragma unroll
    for (int i = 0; i < 2; ++i) {
        const float4* pf = (const float4*)(Utf + ((size_t)(u0 + i) * 256 + 32 * g));
        const float4* ps = (const float4*)(Uts + ((size_t)(u0 + i) * 256 + 32 * g));
#pragma unroll
        for (int jj = 0; jj < 4; ++jj) {
            F4H a; a.f4 = pf[jj];
            F4H c; c.f4 = ps[jj];
#pragma unroll
            for (int m = 0; m < 4; ++m) {
                uf[i][4 * jj + m] = a.h[m];
                us[i][4 * jj + m] = c.h[m];
            }
        }
    }

    if (tid < 8 * 40) h2p[tid] = (_Float16)0.f;

    const size_t base = (size_t)b * SEQ * UNITS;
    // f16 index where this (w,r) group's two h/g values live:
    const int widx = (w >> 1) * 40 + 16 * (w & 1) + 2 * r;

    // Gate-lane state (g==0 only): h_old, f for u0 and u0+1.
    float h_old0 = 0.f, h_old1 = 0.f, f0 = 0.f, f1 = 0.f;
    float2 xf_cur = make_float2(0.f, 0.f);
    unsigned xs_cur = 0;
    if (g == 0) {
        xf_cur = *(const float2*)(xf_out + base + u0);
        xs_cur = *(const unsigned*)(xs16 + base + u0);
    }
    __syncthreads();

    for (int t = 0; t < SEQ; ++t) {
        const int tn = (t + 1 < SEQ) ? t + 1 : t;

        // prefetch next step's xf/xs (used next iteration -> ~full step in flight)
        float2 xf_nxt = make_float2(0.f, 0.f);
        unsigned xs_nxt = 0;
        if (g == 0) {
            xf_nxt = *(const float2*)(xf_out + base + (size_t)tn * UNITS + u0);
            xs_nxt = *(const unsigned*)(xs16 + base + (size_t)tn * UNITS + u0);
        }

        // ---- phase A: h @ U_f partials + in-wave forget gate
        {
            const float4* hv = (const float4*)(h2p + g * 40);
            F4H H0, H1, H2, H3;
            H0.f4 = hv[0]; H1.f4 = hv[1]; H2.f4 = hv[2]; H3.f4 = hv[3];
            float a0 = 0.f, a1 = 0.f;
#pragma unroll
            for (int m = 0; m < 4; ++m) {
                a0 = fdot2(uf[0][m +  0], H0.h[m], a0);
                a1 = fdot2(uf[1][m +  0], H0.h[m], a1);
                a0 = fdot2(uf[0][m +  4], H1.h[m], a0);
                a1 = fdot2(uf[1][m +  4], H1.h[m], a1);
                a0 = fdot2(uf[0][m +  8], H2.h[m], a0);
                a1 = fdot2(uf[1][m +  8], H2.h[m], a1);
                a0 = fdot2(uf[0][m + 12], H3.h[m], a0);
                a1 = fdot2(uf[1][m + 12], H3.h[m], a1);
            }
            a0 = row8_sum(a0);
            a1 = row8_sum(a1);
            if (g == 0) {
                f0 = 1.f / (1.f + __expf(-(xf_cur.x + a0)));
                f1 = 1.f / (1.f + __expf(-(xf_cur.y + a1)));
                half2_t gv;
                gv[0] = (_Float16)(f0 * h_old0);
                gv[1] = (_Float16)(f1 * h_old1);
                *(half2_t*)(g2p + widx) = gv;
            }
        }
        BAR();

        // ---- phase C: (f*h) @ U_s partials + in-wave candidate/update
        {
            const float4* gv4 = (const float4*)(g2p + g * 40);
            F4H G0, G1, G2, G3;
            G0.f4 = gv4[0]; G1.f4 = gv4[1]; G2.f4 = gv4[2]; G3.f4 = gv4[3];
            float c0 = 0.f, c1 = 0.f;
#pragma unroll
            for (int m = 0; m < 4; ++m) {
                c0 = fdot2(us[0][m +  0], G0.h[m], c0);
                c1 = fdot2(us[1][m +  0], G0.h[m], c1);
                c0 = fdot2(us[0][m +  4], G1.h[m], c0);
                c1 = fdot2(us[1][m +  4], G1.h[m], c1);
                c0 = fdot2(us[0][m +  8], G2.h[m], c0);
                c1 = fdot2(us[1][m +  8], G2.h[m], c1);
                c0 = fdot2(us[0][m + 12], G3.h[m], c0);
                c1 = fdot2(us[1][m + 12], G3.h[m], c1);
            }
            c0 = row8_sum(c0);
            c1 = row8_sum(c1);
            if (g == 0) {
                U2H xh; xh.u = xs_cur;
                float z0 = (float)xh.h[0] + c0;
                float z1 = (float)xh.h[1] + c1;
                z0 = fminf(fmaxf(z0, -15.f), 15.f);
                z1 = fminf(fmaxf(z1, -15.f), 15.f);
                float e0 = __expf(2.f * z0);
                float e1 = __expf(2.f * z1);
                float s0 = 1.f - 2.f / (e0 + 1.f);
                float s1 = 1.f - 2.f / (e1 + 1.f);
                float hn0 = h_old0 + f0 * (s0 - h_old0);
                float hn1 = h_old1 + f1 * (s1 - h_old1);
                h_old0 = hn0;
                h_old1 = hn1;
                half2_t hv2;
                hv2[0] = (_Float16)hn0;
                hv2[1] = (_Float16)hn1;
                *(half2_t*)(h2p + widx) = hv2;
                float2 st; st.x = hn0; st.y = hn1;
                *(float2*)(xf_out + base + (size_t)t * UNITS + u0) = st;
                xf_cur = xf_nxt;
                xs_cur = xs_nxt;
            }
        }
        BAR();
    }
}

extern "C" void kernel_launch(void* const* d_in, const int* in_sizes, int n_in,
                              void* d_out, int out_size, void* d_ws, size_t ws_size,
                              hipStream_t stream) {
    (void)in_sizes; (void)n_in; (void)out_size; (void)ws_size;

    const float* X   = (const float*)d_in[0];
    const float* Wf  = (const float*)d_in[1];
    const float* Uf  = (const float*)d_in[2];
    const float* bf  = (const float*)d_in[3];
    const float* Wsm = (const float*)d_in[4];
    const float* Us  = (const float*)d_in[5];
    const float* bs  = (const float*)d_in[6];
    float* out = (float*)d_out;

    // ws layout: xs16 (64 MB) | Utf (128 KB) | Uts (128 KB)
    _Float16* xs16 = (_Float16*)d_ws;
    _Float16* Utf  = xs16 + (size_t)BATCH * SEQ * UNITS;
    _Float16* Uts  = Utf + 256 * 256;

    prep_u<<<256, 256, 0, stream>>>(Uf, Us, Utf, Uts);
    proj_kernel<<<dim3(BATCH * SEQ / 64, 8), 256, 0, stream>>>(X, Wf, bf, Wsm, bs, out, xs16);
    recur_kernel<<<BATCH, 1024, 0, stream>>>(out, xs16, Utf, Uts);
}

// Round 4
// 3614.387 us; speedup vs baseline: 1.1802x; 1.1802x over previous
//
#include <hip/hip_runtime.h>
#include <hip/hip_bf16.h>

#define BATCH 64
#define SEQ 2048
#define IN_DIM 256
#define UNITS 256

typedef _Float16 half2_t __attribute__((ext_vector_type(2)));

__device__ __forceinline__ float fdot2(half2_t a, half2_t b, float c) {
#if __has_builtin(__builtin_amdgcn_fdot2)
    return __builtin_amdgcn_fdot2(a, b, c, false);
#else
    return c + (float)a[0] * (float)b[0] + (float)a[1] * (float)b[1];
#endif
}

// DPP butterfly add over an 8-aligned 8-lane group; all 8 lanes end with sum.
template <int CTRL>
__device__ __forceinline__ float dpp_xor_add(float v) {
    int s = __builtin_amdgcn_update_dpp(0, __float_as_int(v), CTRL, 0xF, 0xF, true);
    return v + __int_as_float(s);
}
__device__ __forceinline__ float row8_sum(float v) {
    v = dpp_xor_add<0xB1>(v);    // quad_perm {1,0,3,2} : xor 1
    v = dpp_xor_add<0x4E>(v);    // quad_perm {2,3,0,1} : xor 2
    v = dpp_xor_add<0x141>(v);   // row_half_mirror     : joins the two quads
    return v;
}

// LDS-only barrier: global loads stay in flight across it.
#define BAR() asm volatile("s_waitcnt lgkmcnt(0)\n\ts_barrier" ::: "memory")

// ---------------------------------------------------------------------------
// Prep: transpose U_f, U_s (K x U, fp32) -> Ut (U x K, f16).
// ---------------------------------------------------------------------------
__global__ void prep_u(const float* __restrict__ Uf, const float* __restrict__ Us,
                       _Float16* __restrict__ Utf, _Float16* __restrict__ Uts) {
    int idx = blockIdx.x * 256 + threadIdx.x;   // 65536 total
    int k = idx >> 8;
    int u = idx & 255;
    Utf[u * 256 + k] = (_Float16)Uf[idx];
    Uts[u * 256 + k] = (_Float16)Us[idx];
}

// ---------------------------------------------------------------------------
// Projection GEMM (unchanged this round): 64x64 tile, fp32.
// ---------------------------------------------------------------------------
__global__ __launch_bounds__(256) void proj_kernel(
    const float* __restrict__ X,
    const float* __restrict__ Wf, const float* __restrict__ bf,
    const float* __restrict__ Wsm, const float* __restrict__ bs,
    float* __restrict__ xf_out, _Float16* __restrict__ xs_out)
{
    __shared__ float Xs[64][65];
    __shared__ float Wsh[64][68];

    const int tid = threadIdx.x;
    const int rt = blockIdx.x;
    const int ct = blockIdx.y;
    const int r0 = rt * 64;
    const bool is_f = ct < 4;
    const int c0 = (ct & 3) * 64;
    const float* W = is_f ? Wf : Wsm;
    const float* bias = is_f ? bf : bs;
    const int tx = tid & 15;
    const int ty = tid >> 4;

    float acc[4][4];
#pragma unroll
    for (int i = 0; i < 4; ++i)
#pragma unroll
        for (int j = 0; j < 4; ++j) acc[i][j] = 0.f;

    for (int kc = 0; kc < IN_DIM; kc += 64) {
        __syncthreads();
#pragma unroll
        for (int i = 0; i < 4; ++i) {
            int f = tid + i * 256;
            int row = f >> 4;
            int kq = f & 15;
            float4 v = *(const float4*)(X + (size_t)(r0 + row) * IN_DIM + kc + kq * 4);
            Xs[row][kq * 4 + 0] = v.x;
            Xs[row][kq * 4 + 1] = v.y;
            Xs[row][kq * 4 + 2] = v.z;
            Xs[row][kq * 4 + 3] = v.w;
        }
#pragma unroll
        for (int i = 0; i < 4; ++i) {
            int f = tid + i * 256;
            int kk = f >> 4;
            int n4 = f & 15;
            float4 v = *(const float4*)(W + (size_t)(kc + kk) * UNITS + c0 + n4 * 4);
            *(float4*)&Wsh[kk][n4 * 4] = v;
        }
        __syncthreads();
#pragma unroll 8
        for (int kk = 0; kk < 64; ++kk) {
            float a0 = Xs[tx * 4 + 0][kk];
            float a1 = Xs[tx * 4 + 1][kk];
            float a2 = Xs[tx * 4 + 2][kk];
            float a3 = Xs[tx * 4 + 3][kk];
            float4 bv = *(const float4*)&Wsh[kk][ty * 4];
            acc[0][0] += a0 * bv.x; acc[0][1] += a0 * bv.y; acc[0][2] += a0 * bv.z; acc[0][3] += a0 * bv.w;
            acc[1][0] += a1 * bv.x; acc[1][1] += a1 * bv.y; acc[1][2] += a1 * bv.z; acc[1][3] += a1 * bv.w;
            acc[2][0] += a2 * bv.x; acc[2][1] += a2 * bv.y; acc[2][2] += a2 * bv.z; acc[2][3] += a2 * bv.w;
            acc[3][0] += a3 * bv.x; acc[3][1] += a3 * bv.y; acc[3][2] += a3 * bv.z; acc[3][3] += a3 * bv.w;
        }
    }

#pragma unroll
    for (int i = 0; i < 4; ++i) {
        int r = r0 + tx * 4 + i;
        int n0 = c0 + ty * 4;
        if (is_f) {
            float4 v;
            v.x = acc[i][0] + bias[n0 + 0];
            v.y = acc[i][1] + bias[n0 + 1];
            v.z = acc[i][2] + bias[n0 + 2];
            v.w = acc[i][3] + bias[n0 + 3];
            *(float4*)(xf_out + (size_t)r * UNITS + n0) = v;
        } else {
#pragma unroll
            for (int j = 0; j < 4; ++j)
                xs_out[(size_t)r * UNITS + n0 + j] = (_Float16)(acc[i][j] + bias[n0 + j]);
        }
    }
}

// ---------------------------------------------------------------------------
// Recurrence v4: 512 threads (8 waves, 2/SIMD) per batch, 2 barriers/step.
// Thread (wave w=tid>>6, r=lane>>3, g=lane&7) accumulates outputs
// u0..u0+3 (u0 = 32w+4r) over k-slice [32g, 32g+32).
//   - weights register-resident: 4 u x 32 k x 2 matrices = 128 VGPRs.
//   - h/g LDS reads: 4 x ds_read_b128, stride-40-f16 groups (conflict-free).
//   - 3-step DPP butterfly leaves ALL 8 lanes with all 4 sums; lane g<4
//     handles the gate math + writes for single unit u0+g (overhead spread
//     across lanes instead of stacked on g==0).
//   - raw lgkmcnt-barrier; xf/xs register prefetch 1 step ahead.
// ---------------------------------------------------------------------------
__global__ __launch_bounds__(512) void recur_kernel(
    float* xf_out,                       // aliases d_out: xf in, h out (no restrict!)
    const _Float16* __restrict__ xs16,   // [B][T][U]
    const _Float16* __restrict__ Utf,    // [U][K] f16
    const _Float16* __restrict__ Uts)    // [U][K] f16
{
    __shared__ __align__(16) _Float16 h2p[8 * 40];   // 8 k-groups x 32 f16 (+8 pad)
    __shared__ __align__(16) _Float16 g2p[8 * 40];

    const int tid = threadIdx.x;
    const int w = tid >> 6;         // 0..7
    const int lane = tid & 63;
    const int g = lane & 7;         // k-group: k in [32g, 32g+32)
    const int r = lane >> 3;        // 0..7
    const int u0 = 32 * w + 4 * r;  // four outputs u0..u0+3
    const int b = blockIdx.x;

    union F4H { float4 f4; half2_t h[4]; };

    // Register-resident weight slices: 16 half2 per u per matrix.
    half2_t uf[4][16], us[4][16];
#pragma unroll
    for (int i = 0; i < 4; ++i) {
        const float4* pf = (const float4*)(Utf + ((size_t)(u0 + i) * 256 + 32 * g));
        const float4* ps = (const float4*)(Uts + ((size_t)(u0 + i) * 256 + 32 * g));
#pragma unroll
        for (int jj = 0; jj < 4; ++jj) {
            F4H a; a.f4 = pf[jj];
            F4H c; c.f4 = ps[jj];
#pragma unroll
            for (int m = 0; m < 4; ++m) {
                uf[i][4 * jj + m] = a.h[m];
                us[i][4 * jj + m] = c.h[m];
            }
        }
    }

    if (tid < 8 * 40) h2p[tid] = (_Float16)0.f;

    const size_t base = (size_t)b * SEQ * UNITS;

    const bool wr = g < 4;                 // this lane owns unit u
    const int u = u0 + (g & 3);
    const int lidx = w * 40 + 4 * r + (g & 3);   // f16 index of h[u] in LDS

    float h_old = 0.f;
    float xf_cur = 0.f;
    float xs_cur = 0.f;
    if (wr) {
        xf_cur = xf_out[base + u];
        xs_cur = (float)xs16[base + u];
    }
    __syncthreads();

    for (int t = 0; t < SEQ; ++t) {
        const int tn = (t + 1 < SEQ) ? t + 1 : t;

        // prefetch next step's xf/xs (registers; consumed end of this step)
        float xf_nxt = 0.f;
        float xs_nxt = 0.f;
        if (wr) {
            xf_nxt = xf_out[base + (size_t)tn * UNITS + u];
            xs_nxt = (float)xs16[base + (size_t)tn * UNITS + u];
        }

        // ---- phase A: h @ U_f partials, DPP reduce, per-lane forget gate
        float f;
        {
            const float4* hv = (const float4*)(h2p + g * 40);
            F4H H0, H1, H2, H3;
            H0.f4 = hv[0]; H1.f4 = hv[1]; H2.f4 = hv[2]; H3.f4 = hv[3];
            float a0 = 0.f, a1 = 0.f, a2 = 0.f, a3 = 0.f;
#pragma unroll
            for (int m = 0; m < 4; ++m) {
                a0 = fdot2(uf[0][m +  0], H0.h[m], a0);
                a1 = fdot2(uf[1][m +  0], H0.h[m], a1);
                a2 = fdot2(uf[2][m +  0], H0.h[m], a2);
                a3 = fdot2(uf[3][m +  0], H0.h[m], a3);
                a0 = fdot2(uf[0][m +  4], H1.h[m], a0);
                a1 = fdot2(uf[1][m +  4], H1.h[m], a1);
                a2 = fdot2(uf[2][m +  4], H1.h[m], a2);
                a3 = fdot2(uf[3][m +  4], H1.h[m], a3);
                a0 = fdot2(uf[0][m +  8], H2.h[m], a0);
                a1 = fdot2(uf[1][m +  8], H2.h[m], a1);
                a2 = fdot2(uf[2][m +  8], H2.h[m], a2);
                a3 = fdot2(uf[3][m +  8], H2.h[m], a3);
                a0 = fdot2(uf[0][m + 12], H3.h[m], a0);
                a1 = fdot2(uf[1][m + 12], H3.h[m], a1);
                a2 = fdot2(uf[2][m + 12], H3.h[m], a2);
                a3 = fdot2(uf[3][m + 12], H3.h[m], a3);
            }
            a0 = row8_sum(a0); a1 = row8_sum(a1);
            a2 = row8_sum(a2); a3 = row8_sum(a3);
            // every lane now has all 4 sums; lane g<4 takes its own
            float av = (g == 0) ? a0 : (g == 1) ? a1 : (g == 2) ? a2 : a3;
            f = 1.f / (1.f + __expf(-(xf_cur + av)));
            if (wr) g2p[lidx] = (_Float16)(f * h_old);
        }
        BAR();

        // ---- phase C: (f*h) @ U_s partials, DPP reduce, per-lane update
        {
            const float4* gv = (const float4*)(g2p + g * 40);
            F4H G0, G1, G2, G3;
            G0.f4 = gv[0]; G1.f4 = gv[1]; G2.f4 = gv[2]; G3.f4 = gv[3];
            float c0 = 0.f, c1 = 0.f, c2 = 0.f, c3 = 0.f;
#pragma unroll
            for (int m = 0; m < 4; ++m) {
                c0 = fdot2(us[0][m +  0], G0.h[m], c0);
                c1 = fdot2(us[1][m +  0], G0.h[m], c1);
                c2 = fdot2(us[2][m +  0], G0.h[m], c2);
                c3 = fdot2(us[3][m +  0], G0.h[m], c3);
                c0 = fdot2(us[0][m +  4], G1.h[m], c0);
                c1 = fdot2(us[1][m +  4], G1.h[m], c1);
                c2 = fdot2(us[2][m +  4], G1.h[m], c2);
                c3 = fdot2(us[3][m +  4], G1.h[m], c3);
                c0 = fdot2(us[0][m +  8], G2.h[m], c0);
                c1 = fdot2(us[1][m +  8], G2.h[m], c1);
                c2 = fdot2(us[2][m +  8], G2.h[m], c2);
                c3 = fdot2(us[3][m +  8], G2.h[m], c3);
                c0 = fdot2(us[0][m + 12], G3.h[m], c0);
                c1 = fdot2(us[1][m + 12], G3.h[m], c1);
                c2 = fdot2(us[2][m + 12], G3.h[m], c2);
                c3 = fdot2(us[3][m + 12], G3.h[m], c3);
            }
            c0 = row8_sum(c0); c1 = row8_sum(c1);
            c2 = row8_sum(c2); c3 = row8_sum(c3);
            float cv = (g == 0) ? c0 : (g == 1) ? c1 : (g == 2) ? c2 : c3;
            // tanh via exp; inf/0 limits give exactly +-1, no clamp needed
            float e = __expf(2.f * (xs_cur + cv));
            float s = 1.f - 2.f / (e + 1.f);
            float hn = h_old + f * (s - h_old);
            if (wr) {
                h_old = hn;
                h2p[lidx] = (_Float16)hn;
                xf_out[base + (size_t)t * UNITS + u] = hn;
                xf_cur = xf_nxt;
                xs_cur = xs_nxt;
            }
        }
        BAR();
    }
}

extern "C" void kernel_launch(void* const* d_in, const int* in_sizes, int n_in,
                              void* d_out, int out_size, void* d_ws, size_t ws_size,
                              hipStream_t stream) {
    (void)in_sizes; (void)n_in; (void)out_size; (void)ws_size;

    const float* X   = (const float*)d_in[0];
    const float* Wf  = (const float*)d_in[1];
    const float* Uf  = (const float*)d_in[2];
    const float* bf  = (const float*)d_in[3];
    const float* Wsm = (const float*)d_in[4];
    const float* Us  = (const float*)d_in[5];
    const float* bs  = (const float*)d_in[6];
    float* out = (float*)d_out;

    // ws layout: xs16 (64 MB) | Utf (128 KB) | Uts (128 KB)
    _Float16* xs16 = (_Float16*)d_ws;
    _Float16* Utf  = xs16 + (size_t)BATCH * SEQ * UNITS;
    _Float16* Uts  = Utf + 256 * 256;

    prep_u<<<256, 256, 0, stream>>>(Uf, Us, Utf, Uts);
    proj_kernel<<<dim3(BATCH * SEQ / 64, 8), 256, 0, stream>>>(X, Wf, bf, Wsm, bs, out, xs16);
    recur_kernel<<<BATCH, 512, 0, stream>>>(out, xs16, Utf, Uts);
}